// Round 1
// baseline (153.128 us; speedup 1.0000x reference)
//
#include <hip/hip_runtime.h>
#include <stdint.h>

typedef __attribute__((ext_vector_type(4))) float f32x4;
typedef __attribute__((ext_vector_type(8))) short short8;

#define NROWS 8192

static __device__ __forceinline__ unsigned int f2bf(float f) {
  unsigned int u = __float_as_uint(f);
  return (u + 0x7fffu + ((u >> 16) & 1u)) >> 16;  // RNE
}
static __device__ __forceinline__ float bf2f(unsigned int h) {
  return __uint_as_float(h << 16);
}

// ---------------------------------------------------------------------------
// Kernel 1: projection (fc2(elu(fc1(z)))) + L2 normalize, f32 compute.
// Output: bf16 rows pre-scaled by sqrt(2*log2(e)) so Gram MFMA output is the
// exp2 argument directly.
// 256 blocks x 256 threads; block = 64 rows. tid: colgrp=tid&31 (4 cols),
// rowgrp=tid>>5 (8 rows). LDS: wT transposed (stride 132 to break bank
// conflicts, float4-aligned) + z/h tile row-major [64][128].
// ---------------------------------------------------------------------------
__global__ __launch_bounds__(256) void proj_kernel(
    const float* __restrict__ z1, const float* __restrict__ z2,
    const float* __restrict__ w1g, const float* __restrict__ b1g,
    const float* __restrict__ w2g, const float* __restrict__ b2g,
    unsigned short* __restrict__ hs1, unsigned short* __restrict__ hs2) {
  __shared__ float wT[128 * 132];
  __shared__ float zb[64 * 128];
  const int tid = threadIdx.x;
  const int cg = tid & 31;
  const int r0 = (tid >> 5) * 8;
  const int zi = blockIdx.x >> 7;
  const int rb = blockIdx.x & 127;
  const float* zg = (zi == 0 ? z1 : z2) + (size_t)rb * 64 * 128;
  unsigned short* outp = (zi == 0 ? hs1 : hs2) + (size_t)rb * 64 * 128;

  {  // stage z tile (coalesced, linear) + w1 transposed
    const f32x4* zg4 = (const f32x4*)zg;
    f32x4* zb4 = (f32x4*)zb;
#pragma unroll
    for (int i = 0; i < 8; ++i) zb4[tid + i * 256] = zg4[tid + i * 256];
    for (int i = tid; i < 128 * 128; i += 256) {
      int j = i >> 7, k = i & 127;
      wT[k * 132 + j] = w1g[i];
    }
  }
  __syncthreads();

  f32x4 acc[8];
#pragma unroll
  for (int rr = 0; rr < 8; ++rr) acc[rr] = f32x4{0.f, 0.f, 0.f, 0.f};

  for (int kc = 0; kc < 32; ++kc) {  // layer 1
    f32x4 wv[4], zv[8];
#pragma unroll
    for (int kk = 0; kk < 4; ++kk) wv[kk] = *(const f32x4*)&wT[(kc * 4 + kk) * 132 + cg * 4];
#pragma unroll
    for (int rr = 0; rr < 8; ++rr) zv[rr] = *(const f32x4*)&zb[(r0 + rr) * 128 + kc * 4];
#pragma unroll
    for (int rr = 0; rr < 8; ++rr)
#pragma unroll
      for (int kk = 0; kk < 4; ++kk) acc[rr] += wv[kk] * zv[rr][kk];
  }

  const f32x4 bias1 = *(const f32x4*)&b1g[cg * 4];
#pragma unroll
  for (int rr = 0; rr < 8; ++rr) {  // bias + ELU (alpha=1)
    f32x4 h = acc[rr] + bias1;
#pragma unroll
    for (int c = 0; c < 4; ++c) h[c] = h[c] > 0.f ? h[c] : expm1f(h[c]);
    acc[rr] = h;
  }
  __syncthreads();  // all reads of zb/wT (layer 1) complete
#pragma unroll
  for (int rr = 0; rr < 8; ++rr)  // h -> zb (same row-major layout)
    *(f32x4*)&zb[(r0 + rr) * 128 + cg * 4] = acc[rr];
  for (int i = tid; i < 128 * 128; i += 256) {  // restage w2
    int j = i >> 7, k = i & 127;
    wT[k * 132 + j] = w2g[i];
  }
  __syncthreads();

#pragma unroll
  for (int rr = 0; rr < 8; ++rr) acc[rr] = f32x4{0.f, 0.f, 0.f, 0.f};
  for (int kc = 0; kc < 32; ++kc) {  // layer 2
    f32x4 wv[4], zv[8];
#pragma unroll
    for (int kk = 0; kk < 4; ++kk) wv[kk] = *(const f32x4*)&wT[(kc * 4 + kk) * 132 + cg * 4];
#pragma unroll
    for (int rr = 0; rr < 8; ++rr) zv[rr] = *(const f32x4*)&zb[(r0 + rr) * 128 + kc * 4];
#pragma unroll
    for (int rr = 0; rr < 8; ++rr)
#pragma unroll
      for (int kk = 0; kk < 4; ++kk) acc[rr] += wv[kk] * zv[rr][kk];
  }

  const f32x4 bias2 = *(const f32x4*)&b2g[cg * 4];
  float ss[8];
#pragma unroll
  for (int rr = 0; rr < 8; ++rr) {
    f32x4 o = acc[rr] + bias2;
    acc[rr] = o;
    ss[rr] = o.x * o.x + o.y * o.y + o.z * o.z + o.w * o.w;
  }
#pragma unroll
  for (int m = 1; m <= 16; m <<= 1)  // reduce over 32 colgrp lanes (stays in half-wave)
#pragma unroll
    for (int rr = 0; rr < 8; ++rr) ss[rr] += __shfl_xor(ss[rr], m, 64);

#pragma unroll
  for (int rr = 0; rr < 8; ++rr) {
    // scale = sqrt(2*log2(e)) / max(||row||, 1e-12)
    float s = 1.6986436005760381f / fmaxf(sqrtf(ss[rr]), 1e-12f);
    f32x4 o = acc[rr] * s;
    uint2 pk;
    pk.x = f2bf(o.x) | (f2bf(o.y) << 16);
    pk.y = f2bf(o.z) | (f2bf(o.w) << 16);
    *(uint2*)&outp[(r0 + rr) * 128 + cg * 4] = pk;
  }
}

// ---------------------------------------------------------------------------
// Kernel 2: fused Gram + exp2 + row-sum. 4 passes: (1,1)->R11 (2,2)->R22
// (1,2)->R12 (2,1)->R21 (R21 row-sums == column sums of exp(between)).
// 256 blocks (pass=blk>>6, rowblock=blk&63) x 512 threads (8 waves, 2x4).
// Block tile 128 rows x 128 cols per iter, K=128 full; A tile in regs after
// one staging; B double-buffered in LDS with XOR swizzle (row&7)<<4.
// ---------------------------------------------------------------------------
__global__ __launch_bounds__(512) void gram_kernel(
    const unsigned short* __restrict__ hs1, const unsigned short* __restrict__ hs2,
    float* __restrict__ R) {
  __shared__ unsigned short Abuf[128 * 128];
  __shared__ unsigned short Bbuf[2][128 * 128];
  __shared__ float redbuf[4][128];

  const int tid = threadIdx.x;
  const int w = tid >> 6;
  const int l = tid & 63;
  const int l16 = l & 15;
  const int lh = l >> 4;
  const int wm = w >> 2;  // 0..1 (row half)
  const int wn = w & 3;   // 0..3 (col quarter)
  const int pass = blockIdx.x >> 6;
  const int rb = blockIdx.x & 63;

  const unsigned short* Ag = (pass == 0 || pass == 2) ? hs1 : hs2;
  const unsigned short* Bg = (pass == 0) ? hs1 : (pass == 1 ? hs2 : (pass == 2 ? hs2 : hs1));

  {  // prologue: stage A tile + B tile 0 (global coalesced -> swizzled LDS)
    int4 va[4], vb0[4];
    const char* asrc = (const char*)(Ag + (size_t)rb * 128 * 128);
    const char* bsrc = (const char*)Bg;
#pragma unroll
    for (int s = 0; s < 4; ++s) {
      int r = w * 16 + s * 4 + lh;
      va[s] = *(const int4*)(asrc + r * 256 + l16 * 16);
      vb0[s] = *(const int4*)(bsrc + r * 256 + l16 * 16);
    }
#pragma unroll
    for (int s = 0; s < 4; ++s) {
      int r = w * 16 + s * 4 + lh;
      int so = r * 256 + ((l16 * 16) ^ ((r & 7) << 4));
      *(int4*)((char*)Abuf + so) = va[s];
      *(int4*)((char*)Bbuf[0] + so) = vb0[s];
    }
  }
  __syncthreads();

  short8 af[4][4];  // A fragments resident in registers for the whole sweep
#pragma unroll
  for (int mf = 0; mf < 4; ++mf)
#pragma unroll
    for (int ks = 0; ks < 4; ++ks) {
      int row = wm * 64 + mf * 16 + l16;
      int cb = (ks * 64 + lh * 16) ^ ((row & 7) << 4);
      af[mf][ks] = *(const short8*)((const char*)Abuf + row * 256 + cb);
    }

  float rs[4][4];
#pragma unroll
  for (int mf = 0; mf < 4; ++mf)
#pragma unroll
    for (int r = 0; r < 4; ++r) rs[mf][r] = 0.f;

  for (int ct = 0; ct < 64; ++ct) {
    const int cur = ct & 1;
    int4 vb[4];
    const bool pf = (ct + 1 < 64);
    if (pf) {  // issue next-tile global loads early (latency hides under MFMA)
      const char* bsrc = (const char*)(Bg + (size_t)(ct + 1) * 128 * 128);
#pragma unroll
      for (int s = 0; s < 4; ++s) {
        int r = w * 16 + s * 4 + lh;
        vb[s] = *(const int4*)(bsrc + r * 256 + l16 * 16);
      }
    }
    short8 bf[2][4];
#pragma unroll
    for (int nf = 0; nf < 2; ++nf)
#pragma unroll
      for (int ks = 0; ks < 4; ++ks) {
        int row = wn * 32 + nf * 16 + l16;
        int cb = (ks * 64 + lh * 16) ^ ((row & 7) << 4);
        bf[nf][ks] = *(const short8*)((const char*)Bbuf[cur] + row * 256 + cb);
      }
#pragma unroll
    for (int mf = 0; mf < 4; ++mf)
#pragma unroll
      for (int nf = 0; nf < 2; ++nf) {
        f32x4 c = f32x4{0.f, 0.f, 0.f, 0.f};
#pragma unroll
        for (int ks = 0; ks < 4; ++ks)
          c = __builtin_amdgcn_mfma_f32_16x16x32_bf16(af[mf][ks], bf[nf][ks], c, 0, 0, 0);
        // inputs pre-scaled: c = (2*log2 e)*s  ->  exp2(c) = exp(2s) = exp(s/TAU)
#pragma unroll
        for (int r = 0; r < 4; ++r) rs[mf][r] += exp2f(c[r]);
      }
    if (pf) {  // write staged regs into the other buffer (T14 split)
      char* dst = (char*)Bbuf[cur ^ 1];
#pragma unroll
      for (int s = 0; s < 4; ++s) {
        int r = w * 16 + s * 4 + lh;
        *(int4*)(dst + r * 256 + ((l16 * 16) ^ ((r & 7) << 4))) = vb[s];
      }
    }
    __syncthreads();
  }

  // reduce over the 16 columns held across lanes (l&15); C/D: col=l&15,
  // row = (l>>4)*4 + reg  [m89]
#pragma unroll
  for (int mf = 0; mf < 4; ++mf)
#pragma unroll
    for (int r = 0; r < 4; ++r) {
      float v = rs[mf][r];
      v += __shfl_xor(v, 1, 64);
      v += __shfl_xor(v, 2, 64);
      v += __shfl_xor(v, 4, 64);
      v += __shfl_xor(v, 8, 64);
      rs[mf][r] = v;
    }
  if (l16 == 0) {
#pragma unroll
    for (int mf = 0; mf < 4; ++mf)
#pragma unroll
      for (int r = 0; r < 4; ++r)
        redbuf[wn][wm * 64 + mf * 16 + lh * 4 + r] = rs[mf][r];
  }
  __syncthreads();
  if (tid < 128) {
    float v = redbuf[0][tid] + redbuf[1][tid] + redbuf[2][tid] + redbuf[3][tid];
    R[pass * NROWS + rb * 128 + tid] = v;
  }
}

// ---------------------------------------------------------------------------
// Kernel 3a: per-row loss + block partial sums (deterministic, no atomics).
// loss_i = -2*s12_ii + 0.5*(log(R11+R12-e^2) + log(R22+R21-e^2))
// s12_ii from f32 dot of the scaled bf16 rows: dot = c*s -> -ln2*dot = -2*s.
// ---------------------------------------------------------------------------
__global__ __launch_bounds__(256) void loss_kernel(
    const unsigned short* __restrict__ hs1, const unsigned short* __restrict__ hs2,
    const float* __restrict__ R, float* __restrict__ partial) {
  const int tid = threadIdx.x;
  const int l = tid & 63;
  const int wv = tid >> 6;
  const int gw = blockIdx.x * 4 + wv;  // 0..255
  const float E2 = 7.3890560989306495f;
  const float LN2 = 0.6931471805599453f;
  float acc = 0.f;
  const unsigned int* h1 = (const unsigned int*)hs1;
  const unsigned int* h2 = (const unsigned int*)hs2;
  for (int t = 0; t < 32; ++t) {
    int i = gw * 32 + t;
    unsigned int a = h1[i * 64 + l];
    unsigned int b = h2[i * 64 + l];
    float p = bf2f(a & 0xffffu) * bf2f(b & 0xffffu) + bf2f(a >> 16) * bf2f(b >> 16);
#pragma unroll
    for (int m = 1; m < 64; m <<= 1) p += __shfl_xor(p, m, 64);
    if (l == 0) {
      float d1 = R[i] + R[2 * NROWS + i] - E2;
      float d2 = R[NROWS + i] + R[3 * NROWS + i] - E2;
      acc += -LN2 * p + 0.5f * (logf(d1) + logf(d2));
    }
  }
  __shared__ float wacc[4];
  if (l == 0) wacc[wv] = acc;
  __syncthreads();
  if (tid == 0) partial[blockIdx.x] = wacc[0] + wacc[1] + wacc[2] + wacc[3];
}

__global__ void loss_final(const float* __restrict__ partial, float* __restrict__ outp) {
  float v = partial[threadIdx.x];
#pragma unroll
  for (int m = 1; m < 64; m <<= 1) v += __shfl_xor(v, m, 64);
  if (threadIdx.x == 0) outp[0] = v * (1.0f / 8192.0f);
}

// ---------------------------------------------------------------------------
extern "C" void kernel_launch(void* const* d_in, const int* in_sizes, int n_in,
                              void* d_out, int out_size, void* d_ws, size_t ws_size,
                              hipStream_t stream) {
  const float* z1 = (const float*)d_in[0];
  const float* z2 = (const float*)d_in[1];
  const float* w1 = (const float*)d_in[2];
  const float* b1 = (const float*)d_in[3];
  const float* w2 = (const float*)d_in[4];
  const float* b2 = (const float*)d_in[5];
  char* ws = (char*)d_ws;
  unsigned short* hs1 = (unsigned short*)ws;                                  // 2 MB
  unsigned short* hs2 = (unsigned short*)(ws + (size_t)2 * 1024 * 1024);      // 2 MB
  float* R = (float*)(ws + (size_t)4 * 1024 * 1024);                          // 128 KB
  float* partial = (float*)(ws + (size_t)4 * 1024 * 1024 + 128 * 1024);       // 256 B
  float* outp = (float*)d_out;

  proj_kernel<<<dim3(256), dim3(256), 0, stream>>>(z1, z2, w1, b1, w2, b2, hs1, hs2);
  gram_kernel<<<dim3(256), dim3(512), 0, stream>>>(hs1, hs2, R);
  loss_kernel<<<dim3(64), dim3(256), 0, stream>>>(hs1, hs2, R, partial);
  loss_final<<<dim3(1), dim3(64), 0, stream>>>(partial, outp);
}